// Round 10
// baseline (76.012 us; speedup 1.0000x reference)
//
#include <hip/hip_runtime.h>
#include <hip/hip_bf16.h>
#include <math.h>

typedef _Float16 half8_t __attribute__((ext_vector_type(8)));
typedef _Float16 half4_t __attribute__((ext_vector_type(4)));
typedef float floatx4 __attribute__((ext_vector_type(4)));

#define TPT 8   // 64-row tiles per block; grid = B/(64*TPT) = 256 = 1 block/CU

// LDS-only barrier (does NOT drain vmcnt): cross-wave ordering is only via
// LDS; keeping vmcnt alive lets the cross-tile A-prefetch span barriers.
__device__ __forceinline__ void lds_barrier() {
    asm volatile("s_waitcnt lgkmcnt(0)" ::: "memory");
    __builtin_amdgcn_s_barrier();
    asm volatile("" ::: "memory");
}

__device__ __forceinline__ float fast_tanh(float x) {
    float e = __expf(2.f * x);
    return 1.f - 2.f / (e + 1.f);
}

// ---------------------------------------------------------------------------
// K0: repack fp32 weights (K x N row-major) into fp16 MFMA B-fragment layout:
// dst[((nt*KS+ks)*64 + lane)*8 + j] = (half) W[ks*32 + (lane>>4)*8 + j][nt*16 + (lane&15)]
// ---------------------------------------------------------------------------
__device__ __forceinline__ void prep_body(const float* __restrict__ W,
                                          _Float16* __restrict__ dst,
                                          int K, int N, int KS, int b) {
    int ks   = b % KS;
    int nt   = b / KS;
    int lane = threadIdx.x;         // 64
    int col  = nt * 16 + (lane & 15);
    int kbase = ks * 32 + ((lane >> 4) << 3);
    half8_t v;
#pragma unroll
    for (int j = 0; j < 8; ++j) {
        int k = kbase + j;
        float x = (k < K && col < N) ? W[(size_t)k * N + col] : 0.f;
        v[j] = (_Float16)x;
    }
    *(half8_t*)(dst + (size_t)(b * 64 + lane) * 8) = v;
}

__global__ void prep_all(const float* __restrict__ W1, const float* __restrict__ W2,
                         const float* __restrict__ W3,
                         _Float16* __restrict__ w1f, _Float16* __restrict__ w2f,
                         _Float16* __restrict__ w3f) {
    int b = blockIdx.x;
    if (b < 64)      prep_body(W1, w1f, 252, 128, 8, b);
    else if (b < 80) prep_body(W2, w2f, 128, 64, 4, b - 64);
    else             prep_body(W3, w3f, 64, 5, 2, b - 80);
}

// ---------------------------------------------------------------------------
// K1: front MLP.  256 blocks x 512 thr (8 waves) = 1 block/CU, TPT=8 tiles of
// 64 rows.  Low occupancy BY DESIGN (2 waves/SIMD, <=256 VGPR): W1 fragments
// fully register-resident (32 frags = 128 VGPR) + W2 (8 frags = 32 VGPR) so
// each LDS A-read feeds 4 (GEMM1) / 2 (GEMM2) MFMAs -> LDS instr count ~2.5x
// lower than the 4-waves/SIMD variant (R7/R8 proved wave count doesn't help).
//   Wave grid 4M x 2N: mw = w>>1 owns rows mw*16..+15, nw = w&1 owns
//   GEMM1 cols nw*64..+63 (4 nt) and GEMM2 cols nw*32..+31 (2 nt).
//   GEMM3: waves 0..3 -> rows w*16..+15, W3 frags from LDS.
// Cross-tile prefetch: 8 x fp32x4/thread (32 VGPR); lds_barrier keeps vmcnt
// alive so the next tile's 64KB/block stays in flight through the compute.
//   LDS 58KB: sA [64][512B]@0, h1 [64][256B]@32768, h2 [64][128B]@49152,
//   W3 frags 2KB@57344.  XOR swizzle (byte ^= (row&7)<<4) everywhere.
// ---------------------------------------------------------------------------
__global__ __launch_bounds__(512, 2) void front_kernel(
    const float* __restrict__ state,
    const _Float16* __restrict__ w1f, const float* __restrict__ b1,
    const _Float16* __restrict__ w2f, const float* __restrict__ b2,
    const _Float16* __restrict__ w3f, const float* __restrict__ b3,
    float* __restrict__ enc, int Btot) {
    __shared__ char lds[59392];
    const int tid = threadIdx.x;    // 0..511
    const int w   = tid >> 6;       // 0..7
    const int l   = tid & 63;
    const int l15 = l & 15;
    const int lhi = l >> 4;
    const int mw  = w >> 1;         // 0..3: row group mw*16..+15
    const int nw  = w & 1;          // 0..1: col half
    const int row0 = blockIdx.x * (64 * TPT);

    // staging geometry: thread -> (srow = tid>>3, chunks c = (tid&7)+8j);
    // chunk = 16B global fp32 (4 cols) -> 8B LDS fp16.  c==63 is the K-pad.
    const int srow = tid >> 3;      // 0..63
    const int sc0  = tid & 7;
    const int sswz = (srow & 7) << 4;

    floatx4 pf[8];   // prefetched A chunks for the NEXT tile (32 VGPR)

#define ISSUE_A(T)                                                          \
    {                                                                       \
        const float* Ar = state + (size_t)(row0 + (T) * 64 + srow) * 252;   \
        _Pragma("unroll")                                                   \
        for (int jj = 0; jj < 8; ++jj) {                                    \
            int c = sc0 + jj * 8;                                           \
            if (c < 63) pf[jj] = *(const floatx4*)(Ar + c * 4);             \
        }                                                                   \
    }

    ISSUE_A(0)

    // ---- W1 B-frags: this wave's 4 nt-tiles (cols nw*64..+63): 128 VGPR ----
    half8_t bw1[4][8];
#pragma unroll
    for (int ntl = 0; ntl < 4; ++ntl)
#pragma unroll
        for (int ks = 0; ks < 8; ++ks)
            bw1[ntl][ks] = *(const half8_t*)(w1f + (size_t)(((nw * 4 + ntl) * 8 + ks) * 64 + l) * 8);

    // ---- W2 B-frags: 2 nt-tiles (cols nw*32..+31): 32 VGPR ----
    half8_t bw2[2][4];
#pragma unroll
    for (int ntl = 0; ntl < 2; ++ntl)
#pragma unroll
        for (int ks = 0; ks < 4; ++ks)
            bw2[ntl][ks] = *(const half8_t*)(w2f + (size_t)(((nw * 2 + ntl) * 4 + ks) * 64 + l) * 8);

    // ---- W3 frags to LDS @57344 (2KB), used by waves 0..3 in GEMM3 ----
    if (tid < 128) {
        const floatx4* s3 = (const floatx4*)w3f;
        *(floatx4*)(lds + 57344 + tid * 16) = s3[tid];
    }

    // hoisted biases
    float bb1[4], bb2[2];
#pragma unroll
    for (int ntl = 0; ntl < 4; ++ntl) bb1[ntl] = b1[(nw * 4 + ntl) * 16 + l15];
#pragma unroll
    for (int ntl = 0; ntl < 2; ++ntl) bb2[ntl] = b2[(nw * 2 + ntl) * 16 + l15];
    const float bb3 = b3[l15 < 5 ? l15 : 4];

#pragma unroll 1
    for (int t = 0; t < TPT; ++t) {
        // ---- stage: pf -> sA (cvt fp32->fp16, swizzled) ----
#pragma unroll
        for (int jj = 0; jj < 8; ++jj) {
            int c = sc0 + jj * 8;
            half4_t h;
            if (c == 63) {
                h = half4_t{0, 0, 0, 0};            // K-pad cols 252..255
            } else {
                floatx4 f = pf[jj];
                h = half4_t{ (_Float16)f[0], (_Float16)f[1], (_Float16)f[2], (_Float16)f[3] };
            }
            *(half4_t*)(lds + (srow << 9) + ((c * 8) ^ sswz)) = h;
        }
        // ---- issue next tile's loads: in flight across ALL of tile t ----
        if (t + 1 < TPT) ISSUE_A(t + 1)
        lds_barrier();                               // sA ready (vmcnt alive)

        // ---- GEMM1: rows mw*16..+15, cols nw*64..+63; A-read feeds 4 MFMA --
        floatx4 acc1[4];
#pragma unroll
        for (int ntl = 0; ntl < 4; ++ntl) acc1[ntl] = floatx4{0, 0, 0, 0};
#pragma unroll
        for (int ks = 0; ks < 8; ++ks) {
            int r = mw * 16 + l15;
            int cb = ks * 64 + lhi * 16;
            half8_t a = *(const half8_t*)(lds + (r << 9) + (cb ^ ((r & 7) << 4)));
#pragma unroll
            for (int ntl = 0; ntl < 4; ++ntl)
                acc1[ntl] = __builtin_amdgcn_mfma_f32_16x16x32_f16(a, bw1[ntl][ks], acc1[ntl], 0, 0, 0);
        }

        // ---- h1 = relu(acc1 + b1) -> LDS @32768 ----
#pragma unroll
        for (int ntl = 0; ntl < 4; ++ntl) {
            int col2 = ((nw * 4 + ntl) * 16 + l15) * 2;
#pragma unroll
            for (int ri = 0; ri < 4; ++ri) {
                int row = mw * 16 + lhi * 4 + ri;
                float v = acc1[ntl][ri] + bb1[ntl];
                v = v > 0.f ? v : 0.f;
                *(_Float16*)(lds + 32768 + (row << 8) + (col2 ^ ((row & 7) << 4))) = (_Float16)v;
            }
        }
        lds_barrier();                               // h1 ready

        // ---- GEMM2: rows mw*16..+15, cols nw*32..+31; A-read feeds 2 MFMA --
        floatx4 acc2[2] = { floatx4{0, 0, 0, 0}, floatx4{0, 0, 0, 0} };
#pragma unroll
        for (int ks = 0; ks < 4; ++ks) {
            int r = mw * 16 + l15;
            int cb = ks * 64 + lhi * 16;
            half8_t a = *(const half8_t*)(lds + 32768 + (r << 8) + (cb ^ ((r & 7) << 4)));
#pragma unroll
            for (int ntl = 0; ntl < 2; ++ntl)
                acc2[ntl] = __builtin_amdgcn_mfma_f32_16x16x32_f16(a, bw2[ntl][ks], acc2[ntl], 0, 0, 0);
        }

        // ---- h2 = relu(acc2 + b2) -> LDS @49152 ----
#pragma unroll
        for (int ntl = 0; ntl < 2; ++ntl) {
            int col2 = ((nw * 2 + ntl) * 16 + l15) * 2;
#pragma unroll
            for (int ri = 0; ri < 4; ++ri) {
                int row = mw * 16 + lhi * 4 + ri;
                float v = acc2[ntl][ri] + bb2[ntl];
                v = v > 0.f ? v : 0.f;
                *(_Float16*)(lds + 49152 + (row << 7) + (col2 ^ ((row & 7) << 4))) = (_Float16)v;
            }
        }
        lds_barrier();                               // h2 ready

        // ---- GEMM3: waves 0..3 -> rows w*16..+15; W3 frags from LDS ----
        if (w < 4) {
            floatx4 acc3 = floatx4{0, 0, 0, 0};
#pragma unroll
            for (int ks = 0; ks < 2; ++ks) {
                int r = w * 16 + l15;
                int cb = ks * 64 + lhi * 16;
                half8_t a  = *(const half8_t*)(lds + 49152 + (r << 7) + (cb ^ ((r & 7) << 4)));
                half8_t bf = *(const half8_t*)(lds + 57344 + (ks * 64 + l) * 16);
                acc3 = __builtin_amdgcn_mfma_f32_16x16x32_f16(a, bf, acc3, 0, 0, 0);
            }
            if (l15 < 5) {
#pragma unroll
                for (int ri = 0; ri < 4; ++ri) {
                    int grow = row0 + t * 64 + w * 16 + lhi * 4 + ri;
                    enc[(size_t)l15 * Btot + grow] = fast_tanh(acc3[ri] + bb3);
                }
            }
        }
        // loop-around: next stage writes sA (last read in GEMM1(t), two
        // barriers back); h1/h2 similarly ordered by >=1 barrier.
    }
#undef ISSUE_A
}

// ---------------------------------------------------------------------------
// K2: quantum circuit + back MLP, one thread per batch row.
// ---------------------------------------------------------------------------
template<int P>
__device__ __forceinline__ void ry_g(float* re, float* im, float c, float s) {
    constexpr int STR = 1 << P;
#pragma unroll
    for (int base = 0; base < 32; base += 2 * STR)
#pragma unroll
        for (int d = 0; d < STR; ++d) {
            int i0 = base + d, i1 = i0 + STR;
            float r0 = re[i0], r1 = re[i1], m0 = im[i0], m1 = im[i1];
            re[i0] = c * r0 - s * r1;  re[i1] = s * r0 + c * r1;
            im[i0] = c * m0 - s * m1;  im[i1] = s * m0 + c * m1;
        }
}

template<int P>
__device__ __forceinline__ void rz_g(float* re, float* im, float c, float s) {
#pragma unroll
    for (int i = 0; i < 32; ++i) {
        float t = ((i >> P) & 1) ? s : -s;
        float r = re[i], m = im[i];
        re[i] = c * r - t * m;
        im[i] = c * m + t * r;
    }
}

template<int PC, int PT>
__device__ __forceinline__ void cnot_g(float* re, float* im) {
#pragma unroll
    for (int i = 0; i < 32; ++i) {
        if (((i >> PC) & 1) && !((i >> PT) & 1)) {
            int j = i | (1 << PT);
            float t;
            t = re[i]; re[i] = re[j]; re[j] = t;
            t = im[i]; im[i] = im[j]; im[j] = t;
        }
    }
}

__global__ __launch_bounds__(256) void back_kernel(
    const float* __restrict__ enc, const float* __restrict__ qp,
    const float* __restrict__ D1, const float* __restrict__ d1,
    const float* __restrict__ D2, const float* __restrict__ d2,
    const float* __restrict__ D3, const float* __restrict__ d3,
    float* __restrict__ out, int Btot) {
    __shared__ float sD1[160], sd1[32], sD2[512], sd2[16], sD3[64], sd3[4];
    __shared__ float sQc[30], sQs[30];
    const int tid = threadIdx.x;
    for (int i = tid; i < 512; i += 256) sD2[i] = D2[i];
    if (tid < 160) sD1[tid] = D1[tid];
    if (tid < 32)  sd1[tid] = d1[tid];
    if (tid < 64)  sD3[tid] = D3[tid];
    if (tid < 16)  sd2[tid] = d2[tid];
    if (tid < 4)   sd3[tid] = d3[tid];
    if (tid < 30) { float h = 0.5f * qp[tid]; sQc[tid] = cosf(h); sQs[tid] = sinf(h); }
    __syncthreads();

    const size_t r = (size_t)blockIdx.x * 256 + tid;

    float cq[5], sq[5];
    const float HPI = 1.57079632679489662f;   // pi/2
#pragma unroll
    for (int i = 0; i < 5; ++i) {
        float a = enc[(size_t)i * Btot + r] * HPI;
        cq[i] = __cosf(a);
        sq[i] = __sinf(a);
    }
    float re[32], im[32];
#pragma unroll
    for (int i = 0; i < 32; ++i) {
        float v = ((i >> 4) & 1) ? sq[0] : cq[0];
        v *= ((i >> 3) & 1) ? sq[1] : cq[1];
        v *= ((i >> 2) & 1) ? sq[2] : cq[2];
        v *= ((i >> 1) & 1) ? sq[3] : cq[3];
        v *= ( i       & 1) ? sq[4] : cq[4];
        re[i] = v;
        im[i] = 0.f;
    }

#pragma unroll
    for (int lay = 0; lay < 3; ++lay) {
        const float* c = sQc + lay * 10;
        const float* s = sQs + lay * 10;
        ry_g<4>(re, im, c[0], s[0]);  rz_g<4>(re, im, c[1], s[1]);
        ry_g<3>(re, im, c[2], s[2]);  rz_g<3>(re, im, c[3], s[3]);
        ry_g<2>(re, im, c[4], s[4]);  rz_g<2>(re, im, c[5], s[5]);
        ry_g<1>(re, im, c[6], s[6]);  rz_g<1>(re, im, c[7], s[7]);
        ry_g<0>(re, im, c[8], s[8]);  rz_g<0>(re, im, c[9], s[9]);
        cnot_g<4, 3>(re, im);
        cnot_g<3, 2>(re, im);
        cnot_g<2, 1>(re, im);
        cnot_g<1, 0>(re, im);
    }

    float q[5] = {0, 0, 0, 0, 0};
#pragma unroll
    for (int i = 0; i < 32; ++i) {
        float p = re[i] * re[i] + im[i] * im[i];
        q[0] += ((i >> 4) & 1) ? -p : p;
        q[1] += ((i >> 3) & 1) ? -p : p;
        q[2] += ((i >> 2) & 1) ? -p : p;
        q[3] += ((i >> 1) & 1) ? -p : p;
        q[4] += ( i       & 1) ? -p : p;
    }

    float h1[32];
#pragma unroll
    for (int j = 0; j < 32; ++j) {
        float a = sd1[j];
#pragma unroll
        for (int k = 0; k < 5; ++k) a += q[k] * sD1[k * 32 + j];
        h1[j] = a > 0.f ? a : 0.f;
    }
    float h2[16];
#pragma unroll
    for (int j = 0; j < 16; ++j) {
        float a = sd2[j];
#pragma unroll
        for (int k = 0; k < 32; ++k) a += h1[k] * sD2[k * 16 + j];
        h2[j] = a > 0.f ? a : 0.f;
    }
    floatx4 o;
#pragma unroll
    for (int j = 0; j < 4; ++j) {
        float a = sd3[j];
#pragma unroll
        for (int k = 0; k < 16; ++k) a += h2[k] * sD3[k * 4 + j];
        o[j] = a;
    }
    *(floatx4*)(out + r * 4) = o;
}

// ---------------------------------------------------------------------------
extern "C" void kernel_launch(void* const* d_in, const int* in_sizes, int n_in,
                              void* d_out, int out_size, void* d_ws, size_t ws_size,
                              hipStream_t stream) {
    const float* state = (const float*)d_in[0];
    const float* W1 = (const float*)d_in[1];
    const float* b1 = (const float*)d_in[2];
    const float* W2 = (const float*)d_in[3];
    const float* b2 = (const float*)d_in[4];
    const float* W3 = (const float*)d_in[5];
    const float* b3 = (const float*)d_in[6];
    const float* qp = (const float*)d_in[7];
    const float* D1 = (const float*)d_in[8];
    const float* d1 = (const float*)d_in[9];
    const float* D2 = (const float*)d_in[10];
    const float* d2 = (const float*)d_in[11];
    const float* D3 = (const float*)d_in[12];
    const float* d3 = (const float*)d_in[13];
    float* out = (float*)d_out;

    const int B = in_sizes[0] / 252;     // 131072

    char* ws = (char*)d_ws;
    _Float16* w1f = (_Float16*)ws;                         // 64 KB
    _Float16* w2f = (_Float16*)(ws + 65536);               // 16 KB
    _Float16* w3f = (_Float16*)(ws + 65536 + 16384);       // 2 KB
    float*    enc = (float*)(ws + 65536 + 16384 + 2048);   // SoA [5][B] fp32

    prep_all<<<82, 64, 0, stream>>>(W1, W2, W3, w1f, w2f, w3f);
    front_kernel<<<B / (64 * TPT), 512, 0, stream>>>(state, w1f, b1, w2f, b2, w3f, b3, enc, B);
    back_kernel<<<B / 256, 256, 0, stream>>>(enc, qp, D1, d1, D2, d2, D3, d3, out, B);
}

// Round 11
// 54.290 us; speedup vs baseline: 1.4001x; 1.4001x over previous
//
#include <hip/hip_runtime.h>
#include <hip/hip_bf16.h>
#include <math.h>

typedef _Float16 half8_t __attribute__((ext_vector_type(8)));
typedef _Float16 half4_t __attribute__((ext_vector_type(4)));
typedef float floatx4 __attribute__((ext_vector_type(4)));

#define TPT 8   // 32-row tiles per block; grid = B/(32*TPT) = 512 = 2 blocks/CU

// LDS-only barrier (does NOT drain vmcnt): cross-wave ordering is only via
// LDS; keeping vmcnt alive lets the cross-tile A-prefetch span barriers.
__device__ __forceinline__ void lds_barrier() {
    asm volatile("s_waitcnt lgkmcnt(0)" ::: "memory");
    __builtin_amdgcn_s_barrier();
    asm volatile("" ::: "memory");
}

__device__ __forceinline__ float fast_tanh(float x) {
    float e = __expf(2.f * x);
    return 1.f - 2.f / (e + 1.f);
}

// ---------------------------------------------------------------------------
// K0: repack fp32 weights (K x N row-major) into fp16 MFMA B-fragment layout:
// dst[((nt*KS+ks)*64 + lane)*8 + j] = (half) W[ks*32 + (lane>>4)*8 + j][nt*16 + (lane&15)]
// ---------------------------------------------------------------------------
__device__ __forceinline__ void prep_body(const float* __restrict__ W,
                                          _Float16* __restrict__ dst,
                                          int K, int N, int KS, int b) {
    int ks   = b % KS;
    int nt   = b / KS;
    int lane = threadIdx.x;         // 64
    int col  = nt * 16 + (lane & 15);
    int kbase = ks * 32 + ((lane >> 4) << 3);
    half8_t v;
#pragma unroll
    for (int j = 0; j < 8; ++j) {
        int k = kbase + j;
        float x = (k < K && col < N) ? W[(size_t)k * N + col] : 0.f;
        v[j] = (_Float16)x;
    }
    *(half8_t*)(dst + (size_t)(b * 64 + lane) * 8) = v;
}

__global__ void prep_all(const float* __restrict__ W1, const float* __restrict__ W2,
                         const float* __restrict__ W3,
                         _Float16* __restrict__ w1f, _Float16* __restrict__ w2f,
                         _Float16* __restrict__ w3f) {
    int b = blockIdx.x;
    if (b < 64)      prep_body(W1, w1f, 252, 128, 8, b);
    else if (b < 80) prep_body(W2, w2f, 128, 64, 4, b - 64);
    else             prep_body(W3, w3f, 64, 5, 2, b - 80);
}

// ---------------------------------------------------------------------------
// K1: front MLP.  512 blocks x 512 thr (8 waves), TPT=8 tiles of 32 rows,
// 2 blocks/CU.  TWO-PHASE / TWO-BARRIER pipeline with double-buffered sA:
//   P1(t) = { G3(t-1) [waves 0,1]  ||  G1(t) reads sA[t&1]  ||  h1 writes }
//   bar
//   P2(t) = { G2(t) || h2 writes || stage(t+1)->sA[(t+1)&1] || issue A(t+2) }
//   bar
// Staging and GEMM3 hide under G1/G2; barriers/tile: 3 -> 2.
// Work split (R8, proven): G1: wave w -> cols w*16..+15 (8 W1 frags in VGPR);
// G2: wave w -> (mi=w>>2, nt=w&3) 16x16 tile, B-frags from LDS; G3: waves 0,1.
//   LDS 62KB: sA 2x16KB @0/@16384, h1 8KB @32768, h2 4KB @40960,
//   W2 frags 16KB @45056, W3 frags 2KB @61440.  XOR swizzle everywhere.
// ---------------------------------------------------------------------------
__global__ __launch_bounds__(512, 4) void front_kernel(
    const float* __restrict__ state,
    const _Float16* __restrict__ w1f, const float* __restrict__ b1,
    const _Float16* __restrict__ w2f, const float* __restrict__ b2,
    const _Float16* __restrict__ w3f, const float* __restrict__ b3,
    float* __restrict__ enc, int Btot) {
    __shared__ char lds[63488];
    const int tid = threadIdx.x;    // 0..511
    const int w   = tid >> 6;       // 0..7
    const int l   = tid & 63;
    const int l15 = l & 15;
    const int lhi = l >> 4;
    const int row0 = blockIdx.x * (32 * TPT);

    // staging geometry: thread -> (srow = tid>>4, chunks c = (tid&15)+16j);
    // chunk = 16B global fp32 (4 cols) -> 8B LDS fp16.  c==63 is the K-pad.
    const int srow = tid >> 4;      // 0..31
    const int sc0  = tid & 15;
    const int sswz = (srow & 7) << 4;

    floatx4 pf[4];   // prefetched A chunks for a future tile (16 VGPR)

#define ISSUE_A(T)                                                          \
    {                                                                       \
        const float* Ar = state + (size_t)(row0 + (T) * 32 + srow) * 252;   \
        _Pragma("unroll")                                                   \
        for (int jj = 0; jj < 4; ++jj) {                                    \
            int c = sc0 + jj * 16;                                          \
            if (c < 63) pf[jj] = *(const floatx4*)(Ar + c * 4);             \
        }                                                                   \
    }

#define STAGE(T)                                                            \
    {                                                                       \
        int sab = (((T) & 1) << 14);                                        \
        _Pragma("unroll")                                                   \
        for (int jj = 0; jj < 4; ++jj) {                                    \
            int c = sc0 + jj * 16;                                          \
            half4_t h;                                                      \
            if (c == 63) {                                                  \
                h = half4_t{0, 0, 0, 0};                                    \
            } else {                                                        \
                floatx4 f = pf[jj];                                         \
                h = half4_t{ (_Float16)f[0], (_Float16)f[1],                \
                             (_Float16)f[2], (_Float16)f[3] };              \
            }                                                               \
            *(half4_t*)(lds + sab + (srow << 9) + ((c * 8) ^ sswz)) = h;    \
        }                                                                   \
    }

    ISSUE_A(0)

    // ---- W1 B-frags for this wave's N-slice (nt = w): 8 frags, 32 VGPR ----
    half8_t bw1[8];
#pragma unroll
    for (int ks = 0; ks < 8; ++ks)
        bw1[ks] = *(const half8_t*)(w1f + (size_t)((w * 8 + ks) * 64 + l) * 8);

    // ---- copy W2/W3 fragment data into LDS (once per block) ----
    {
        const floatx4* s2 = (const floatx4*)w2f;          // 1024 x 16B
        *(floatx4*)(lds + 45056 + tid * 16)        = s2[tid];
        *(floatx4*)(lds + 45056 + 8192 + tid * 16) = s2[512 + tid];
        if (tid < 128) {
            const floatx4* s3 = (const floatx4*)w3f;      // 128 x 16B
            *(floatx4*)(lds + 61440 + tid * 16) = s3[tid];
        }
    }

    // hoisted biases
    const float bb1 = b1[w * 16 + l15];
    const float bb2 = b2[(w & 3) * 16 + l15];
    const float bb3 = b3[l15 < 5 ? l15 : 4];

    const int mi2 = w >> 2;        // GEMM2 row-tile
    const int nt2 = w & 3;         // GEMM2 col-tile

    // ---- prologue: stage tile 0, issue tile 1 ----
    STAGE(0)
    ISSUE_A(1)
    lds_barrier();

#pragma unroll
    for (int t = 0; t < TPT; ++t) {
        // ================= P1: G3(t-1) || G1(t) || h1(t) =================
        if (w < 2 && t > 0) {
            floatx4 acc3 = floatx4{0, 0, 0, 0};
#pragma unroll
            for (int ks = 0; ks < 2; ++ks) {
                int r = w * 16 + l15;
                int cb = ks * 64 + lhi * 16;
                half8_t a  = *(const half8_t*)(lds + 40960 + (r << 7) + (cb ^ ((r & 7) << 4)));
                half8_t bf = *(const half8_t*)(lds + 61440 + (ks * 64 + l) * 16);
                acc3 = __builtin_amdgcn_mfma_f32_16x16x32_f16(a, bf, acc3, 0, 0, 0);
            }
            if (l15 < 5) {
#pragma unroll
                for (int ri = 0; ri < 4; ++ri) {
                    int grow = row0 + (t - 1) * 32 + w * 16 + lhi * 4 + ri;
                    enc[(size_t)l15 * Btot + grow] = fast_tanh(acc3[ri] + bb3);
                }
            }
        }

        // ---- GEMM1: [32 x 256] @ [256 x 16(cols w*16..)] from sA[t&1] ----
        const int sab = (t & 1) << 14;
        floatx4 acc1[2] = { floatx4{0, 0, 0, 0}, floatx4{0, 0, 0, 0} };
#pragma unroll
        for (int ks = 0; ks < 8; ++ks) {
            int cb = ks * 64 + lhi * 16;
#pragma unroll
            for (int mi = 0; mi < 2; ++mi) {
                int r = mi * 16 + l15;
                half8_t a = *(const half8_t*)(lds + sab + (r << 9) + (cb ^ ((r & 7) << 4)));
                acc1[mi] = __builtin_amdgcn_mfma_f32_16x16x32_f16(a, bw1[ks], acc1[mi], 0, 0, 0);
            }
        }

        // ---- h1 = relu(acc1 + b1) -> LDS @32768, col = w*16+l15 ----
        {
            int col2 = (w * 16 + l15) * 2;
#pragma unroll
            for (int mi = 0; mi < 2; ++mi)
#pragma unroll
                for (int ri = 0; ri < 4; ++ri) {
                    int row = mi * 16 + lhi * 4 + ri;
                    float v = acc1[mi][ri] + bb1;
                    v = v > 0.f ? v : 0.f;
                    *(_Float16*)(lds + 32768 + (row << 8) + (col2 ^ ((row & 7) << 4))) = (_Float16)v;
                }
        }
        lds_barrier();

        // ======== P2: G2(t) || h2(t) || stage(t+1) || issue(t+2) =========
        floatx4 acc2 = floatx4{0, 0, 0, 0};
#pragma unroll
        for (int ks = 0; ks < 4; ++ks) {
            int r = mi2 * 16 + l15;
            int cb = ks * 64 + lhi * 16;
            half8_t a  = *(const half8_t*)(lds + 32768 + (r << 8) + (cb ^ ((r & 7) << 4)));
            half8_t bf = *(const half8_t*)(lds + 45056 + ((nt2 * 4 + ks) * 64 + l) * 16);
            acc2 = __builtin_amdgcn_mfma_f32_16x16x32_f16(a, bf, acc2, 0, 0, 0);
        }

        // ---- h2 = relu(acc2 + b2) -> LDS @40960 ----
        {
            int col2 = (nt2 * 16 + l15) * 2;
#pragma unroll
            for (int ri = 0; ri < 4; ++ri) {
                int row = mi2 * 16 + lhi * 4 + ri;
                float v = acc2[ri] + bb2;
                v = v > 0.f ? v : 0.f;
                *(_Float16*)(lds + 40960 + (row << 7) + (col2 ^ ((row & 7) << 4))) = (_Float16)v;
            }
        }

        // ---- stage(t+1) into sA[(t+1)&1]; issue loads for t+2 ----
        if (t + 1 < TPT) {
            STAGE(t + 1)
            if (t + 2 < TPT) ISSUE_A(t + 2)
        }
        lds_barrier();
    }

    // ---- epilogue: G3 for the last tile ----
    if (w < 2) {
        floatx4 acc3 = floatx4{0, 0, 0, 0};
#pragma unroll
        for (int ks = 0; ks < 2; ++ks) {
            int r = w * 16 + l15;
            int cb = ks * 64 + lhi * 16;
            half8_t a  = *(const half8_t*)(lds + 40960 + (r << 7) + (cb ^ ((r & 7) << 4)));
            half8_t bf = *(const half8_t*)(lds + 61440 + (ks * 64 + l) * 16);
            acc3 = __builtin_amdgcn_mfma_f32_16x16x32_f16(a, bf, acc3, 0, 0, 0);
        }
        if (l15 < 5) {
#pragma unroll
            for (int ri = 0; ri < 4; ++ri) {
                int grow = row0 + (TPT - 1) * 32 + w * 16 + lhi * 4 + ri;
                enc[(size_t)l15 * Btot + grow] = fast_tanh(acc3[ri] + bb3);
            }
        }
    }
#undef ISSUE_A
#undef STAGE
}

// ---------------------------------------------------------------------------
// K2: quantum circuit + back MLP, one thread per batch row.
// Layer-0 single-qubit gates (RY,RZ) are folded analytically into the per-wire
// encoding factors (state is a product state until the first CNOT); the 32
// complex amplitudes are then tree-built (saves ~20% VALU vs gate-by-gate).
// wire w <-> bit (4-w) of the flat amplitude index.
// ---------------------------------------------------------------------------
template<int P>
__device__ __forceinline__ void ry_g(float* re, float* im, float c, float s) {
    constexpr int STR = 1 << P;
#pragma unroll
    for (int base = 0; base < 32; base += 2 * STR)
#pragma unroll
        for (int d = 0; d < STR; ++d) {
            int i0 = base + d, i1 = i0 + STR;
            float r0 = re[i0], r1 = re[i1], m0 = im[i0], m1 = im[i1];
            re[i0] = c * r0 - s * r1;  re[i1] = s * r0 + c * r1;
            im[i0] = c * m0 - s * m1;  im[i1] = s * m0 + c * m1;
        }
}

template<int P>
__device__ __forceinline__ void rz_g(float* re, float* im, float c, float s) {
#pragma unroll
    for (int i = 0; i < 32; ++i) {
        float t = ((i >> P) & 1) ? s : -s;
        float r = re[i], m = im[i];
        re[i] = c * r - t * m;
        im[i] = c * m + t * r;
    }
}

template<int PC, int PT>
__device__ __forceinline__ void cnot_g(float* re, float* im) {
#pragma unroll
    for (int i = 0; i < 32; ++i) {
        if (((i >> PC) & 1) && !((i >> PT) & 1)) {
            int j = i | (1 << PT);
            float t;
            t = re[i]; re[i] = re[j]; re[j] = t;
            t = im[i]; im[i] = im[j]; im[j] = t;
        }
    }
}

// expand product state by one wire at bit position P with factor (a, b)
template<int P>
__device__ __forceinline__ void expand_g(float* re, float* im,
                                         float arv, float aiv, float brv, float biv) {
#pragma unroll
    for (int base = 0; base < 32; base += (2 << P)) {
        float cr = re[base], ci = im[base];
        re[base + (1 << P)] = cr * brv - ci * biv;
        im[base + (1 << P)] = cr * biv + ci * brv;
        re[base] = cr * arv - ci * aiv;
        im[base] = cr * aiv + ci * arv;
    }
}

__global__ __launch_bounds__(256) void back_kernel(
    const float* __restrict__ enc, const float* __restrict__ qp,
    const float* __restrict__ D1, const float* __restrict__ d1,
    const float* __restrict__ D2, const float* __restrict__ d2,
    const float* __restrict__ D3, const float* __restrict__ d3,
    float* __restrict__ out, int Btot) {
    __shared__ float sD1[160], sd1[32], sD2[512], sd2[16], sD3[64], sd3[4];
    __shared__ float sQc[20], sQs[20];          // layers 1,2 gate half-angles
    __shared__ float ryh[5], rzc0[5], rzs0[5];  // layer 0 folded params
    const int tid = threadIdx.x;
    for (int i = tid; i < 512; i += 256) sD2[i] = D2[i];
    if (tid < 160) sD1[tid] = D1[tid];
    if (tid < 32)  sd1[tid] = d1[tid];
    if (tid < 64)  sD3[tid] = D3[tid];
    if (tid < 16)  sd2[tid] = d2[tid];
    if (tid < 4)   sd3[tid] = d3[tid];
    if (tid < 20) { float h = 0.5f * qp[10 + tid]; sQc[tid] = __cosf(h); sQs[tid] = __sinf(h); }
    if (tid < 5) {
        ryh[tid] = 0.5f * qp[2 * tid];
        float h = 0.5f * qp[2 * tid + 1];
        rzc0[tid] = __cosf(h);
        rzs0[tid] = __sinf(h);
    }
    __syncthreads();

    const size_t r = (size_t)blockIdx.x * 256 + tid;

    // per-wire factors: RZ(qp)·RY(enc*pi + qp)|0>  (layer-0 folded)
    const float HPI = 1.57079632679489662f;   // pi/2
    float ar[5], ai[5], br[5], bi[5];
#pragma unroll
    for (int i = 0; i < 5; ++i) {
        float h = enc[(size_t)i * Btot + r] * HPI + ryh[i];
        float ch = __cosf(h), sh = __sinf(h);
        ar[i] = ch * rzc0[i];  ai[i] = -ch * rzs0[i];
        br[i] = sh * rzc0[i];  bi[i] =  sh * rzs0[i];
    }

    // tree-build the 32 complex amplitudes (wire 0 = bit 4)
    float re[32], im[32];
    re[0] = ar[0]; im[0] = ai[0]; re[16] = br[0]; im[16] = bi[0];
    expand_g<3>(re, im, ar[1], ai[1], br[1], bi[1]);
    expand_g<2>(re, im, ar[2], ai[2], br[2], bi[2]);
    expand_g<1>(re, im, ar[3], ai[3], br[3], bi[3]);
    expand_g<0>(re, im, ar[4], ai[4], br[4], bi[4]);

    // layer 0 CNOTs
    cnot_g<4, 3>(re, im);
    cnot_g<3, 2>(re, im);
    cnot_g<2, 1>(re, im);
    cnot_g<1, 0>(re, im);

    // layers 1, 2 (full)
#pragma unroll
    for (int lay = 0; lay < 2; ++lay) {
        const float* c = sQc + lay * 10;
        const float* s = sQs + lay * 10;
        ry_g<4>(re, im, c[0], s[0]);  rz_g<4>(re, im, c[1], s[1]);
        ry_g<3>(re, im, c[2], s[2]);  rz_g<3>(re, im, c[3], s[3]);
        ry_g<2>(re, im, c[4], s[4]);  rz_g<2>(re, im, c[5], s[5]);
        ry_g<1>(re, im, c[6], s[6]);  rz_g<1>(re, im, c[7], s[7]);
        ry_g<0>(re, im, c[8], s[8]);  rz_g<0>(re, im, c[9], s[9]);
        cnot_g<4, 3>(re, im);
        cnot_g<3, 2>(re, im);
        cnot_g<2, 1>(re, im);
        cnot_g<1, 0>(re, im);
    }

    float q[5] = {0, 0, 0, 0, 0};
#pragma unroll
    for (int i = 0; i < 32; ++i) {
        float p = re[i] * re[i] + im[i] * im[i];
        q[0] += ((i >> 4) & 1) ? -p : p;
        q[1] += ((i >> 3) & 1) ? -p : p;
        q[2] += ((i >> 2) & 1) ? -p : p;
        q[3] += ((i >> 1) & 1) ? -p : p;
        q[4] += ( i       & 1) ? -p : p;
    }

    float h1[32];
#pragma unroll
    for (int j = 0; j < 32; ++j) {
        float a = sd1[j];
#pragma unroll
        for (int k = 0; k < 5; ++k) a += q[k] * sD1[k * 32 + j];
        h1[j] = a > 0.f ? a : 0.f;
    }
    float h2[16];
#pragma unroll
    for (int j = 0; j < 16; ++j) {
        float a = sd2[j];
#pragma unroll
        for (int k = 0; k < 32; ++k) a += h1[k] * sD2[k * 16 + j];
        h2[j] = a > 0.f ? a : 0.f;
    }
    floatx4 o;
#pragma unroll
    for (int j = 0; j < 4; ++j) {
        float a = sd3[j];
#pragma unroll
        for (int k = 0; k < 16; ++k) a += h2[k] * sD3[k * 4 + j];
        o[j] = a;
    }
    *(floatx4*)(out + r * 4) = o;
}

// ---------------------------------------------------------------------------
extern "C" void kernel_launch(void* const* d_in, const int* in_sizes, int n_in,
                              void* d_out, int out_size, void* d_ws, size_t ws_size,
                              hipStream_t stream) {
    const float* state = (const float*)d_in[0];
    const float* W1 = (const float*)d_in[1];
    const float* b1 = (const float*)d_in[2];
    const float* W2 = (const float*)d_in[3];
    const float* b2 = (const float*)d_in[4];
    const float* W3 = (const float*)d_in[5];
    const float* b3 = (const float*)d_in[6];
    const float* qp = (const float*)d_in[7];
    const float* D1 = (const float*)d_in[8];
    const float* d1 = (const float*)d_in[9];
    const float* D2 = (const float*)d_in[10];
    const float* d2 = (const float*)d_in[11];
    const float* D3 = (const float*)d_in[12];
    const float* d3 = (const float*)d_in[13];
    float* out = (float*)d_out;

    const int B = in_sizes[0] / 252;     // 131072

    char* ws = (char*)d_ws;
    _Float16* w1f = (_Float16*)ws;                         // 64 KB
    _Float16* w2f = (_Float16*)(ws + 65536);               // 16 KB
    _Float16* w3f = (_Float16*)(ws + 65536 + 16384);       // 2 KB
    float*    enc = (float*)(ws + 65536 + 16384 + 2048);   // SoA [5][B] fp32

    prep_all<<<82, 64, 0, stream>>>(W1, W2, W3, w1f, w2f, w3f);
    front_kernel<<<B / (32 * TPT), 512, 0, stream>>>(state, w1f, b1, w2f, b2, w3f, b3, enc, B);
    back_kernel<<<B / 256, 256, 0, stream>>>(enc, qp, D1, d1, D2, d2, D3, d3, out, B);
}